// Round 9
// baseline (705.773 us; speedup 1.0000x reference)
//
#include <hip/hip_runtime.h>
#include <hip/hip_bf16.h>
#include <cstddef>
#include <cstdint>

#define B_  512
#define L_  200
#define D_  256
#define K_  2048
#define BL_ (B_ * L_)
#define CUS 4          // K-split factor (512 codes per block)
#define NCH 16         // chunks of 32 codes per block

typedef __bf16 bf16x8 __attribute__((ext_vector_type(8)));
typedef float  f32x16 __attribute__((ext_vector_type(16)));

#define GL_LDS(g, l) __builtin_amdgcn_global_load_lds(                          \
    (const __attribute__((address_space(1))) void*)(g),                         \
    (__attribute__((address_space(3))) void*)(l), 16, 0, 0)

__device__ inline ushort f2bf(float f) {   // RNE float->bf16 (no NaN in data)
    union { float f; uint u; } a; a.f = f;
    uint r = a.u + 0x7FFFu + ((a.u >> 16) & 1u);
    return (ushort)(r >> 16);
}

// ---------------------------------------------------------------------------
// prep: cnorm[k] = ||c_k||^2 ; cnormR = acc-layout cnorm + 16 (positive-score
// bias; |2 e.c| <= 12 for this data); bf16 row-major codebook copy.
// acc row r = 4h + (j&3) + 8*(j>>2)  ->  cnormR[chunkbase + h*16 + j]
// ---------------------------------------------------------------------------
__global__ __launch_bounds__(256) void prep_kernel(const float* __restrict__ cb,
                                                   float* __restrict__ cnorm,
                                                   float* __restrict__ cnormR,
                                                   ushort* __restrict__ cbbf) {
    int code = (blockIdx.x * 256 + threadIdx.x) >> 6;
    int lane = threadIdx.x & 63;
    float4 v = ((const float4*)(cb + (size_t)code * D_))[lane];
    float s = v.x * v.x + v.y * v.y + v.z * v.z + v.w * v.w;
    #pragma unroll
    for (int off = 32; off; off >>= 1) s += __shfl_down(s, off);
    union { ushort us[4]; uint2 u2; } pk;
    pk.us[0] = f2bf(v.x); pk.us[1] = f2bf(v.y); pk.us[2] = f2bf(v.z); pk.us[3] = f2bf(v.w);
    ((uint2*)(cbbf + (size_t)code * D_))[lane] = pk.u2;
    if (lane == 0) {
        cnorm[code] = s;
        int r = code & 31;
        int h = (r >> 2) & 1;
        int j = (r & 3) | ((r >> 3) << 2);
        cnormR[(code & ~31) | (h << 4) | j] = s + 16.0f;
    }
}

// ---------------------------------------------------------------------------
// gemm_top2 v7: block = 4 waves x 64 positions (256 pos) x 512 codes (cu).
// One 32KB LDS dbuf feeds all 4 waves (2x staging efficiency vs R7).
// acc init = cnormR (+16) -> acc == positive score. Selection = per-lane
// group minima (j<8 / j>=8) of packed keys (score[31:11] | code[10:0]),
// 3 VALU/score; endgame -> exact top-2 of the 4 h-merged group minima.
// ---------------------------------------------------------------------------
struct CN4 { float4 a, b, c, d; };

__device__ inline CN4 ldcn(const float* p) {
    CN4 r;
    r.a = ((const float4*)p)[0];
    r.b = ((const float4*)p)[1];
    r.c = ((const float4*)p)[2];
    r.d = ((const float4*)p)[3];
    return r;
}

// stage chunk CIDX (32 codes x 512B) into BUF; 4 waves x 4 insts x 64 lanes.
// unit u of code row n stored at LDS unit n*32 + (u ^ (n&7)).
#define STAGE(CIDX, BUF) {                                                      \
    int wub = __builtin_amdgcn_readfirstlane((t >> 6) * 256);                   \
    _Pragma("unroll")                                                           \
    for (int i_ = 0; i_ < 4; ++i_) {                                            \
      int slot = wub + i_ * 64 + (t & 63);                                      \
      int n_ = slot >> 5, up_ = slot & 31;                                      \
      int u_ = up_ ^ (n_ & 7);                                                  \
      GL_LDS(cbbf + (((size_t)((cu << 9) + ((CIDX) << 5) + n_)) << 8) + (u_ << 3), \
             (char*)(BUF) + (size_t)(wub + i_ * 64) * 16);                      \
    } }

#define PROCSEL(BUF, NC, CN) {                                                  \
    f32x16 A0, A1;                                                              \
    A0[0]=(CN).a.x; A0[1]=(CN).a.y; A0[2]=(CN).a.z; A0[3]=(CN).a.w;             \
    A0[4]=(CN).b.x; A0[5]=(CN).b.y; A0[6]=(CN).b.z; A0[7]=(CN).b.w;             \
    A0[8]=(CN).c.x; A0[9]=(CN).c.y; A0[10]=(CN).c.z; A0[11]=(CN).c.w;           \
    A0[12]=(CN).d.x; A0[13]=(CN).d.y; A0[14]=(CN).d.z; A0[15]=(CN).d.w;         \
    A1 = A0;                                                                    \
    _Pragma("unroll")                                                           \
    for (int s_ = 0; s_ < 16; ++s_) {                                           \
      bf16x8 aF = *(const bf16x8*)((const char*)(BUF) +                         \
                    (((l31 << 5) + ((2 * s_ + h) ^ swz)) << 4));                \
      A0 = __builtin_amdgcn_mfma_f32_32x32x16_bf16(aF, bfrag[0][s_], A0, 0,0,0);\
      A1 = __builtin_amdgcn_mfma_f32_32x32x16_bf16(aF, bfrag[1][s_], A1, 0,0,0);\
    }                                                                           \
    uint kbase = (uint)((cu << 9) | ((NC) << 5)) | h4;                          \
    _Pragma("unroll")                                                           \
    for (int j_ = 0; j_ < 16; ++j_) {                                           \
      uint idx_ = kbase | (uint)((j_ & 3) + 8 * (j_ >> 2));                     \
      uint k0_ = (__float_as_uint(A0[j_]) & 0xFFFFF800u) | idx_;                \
      uint k1_ = (__float_as_uint(A1[j_]) & 0xFFFFF800u) | idx_;                \
      if (j_ < 8) { g0a = min(g0a, k0_); g0b = min(g0b, k1_); }                 \
      else        { g1a = min(g1a, k0_); g1b = min(g1b, k1_); }                 \
    } }

__global__ __launch_bounds__(256, 2) void gemm_top2_kernel(
    const int* __restrict__ ids, const int* __restrict__ masks,
    const float* __restrict__ table, const ushort* __restrict__ cbbf,
    const float* __restrict__ cnormR, uint2* __restrict__ cand) {

  __shared__ ushort cbuf0[32 * 256];   // 16 KB
  __shared__ ushort cbuf1[32 * 256];   // 16 KB

  const int t    = threadIdx.x;
  const int lane = t & 63;
  const int l31  = lane & 31;
  const int h    = lane >> 5;
  const int w    = t >> 6;
  const int ptile = blockIdx.x >> 2;
  const int cu    = blockIdx.x & 3;
  const int swz  = l31 & 7;
  const uint h4  = (uint)(h << 2);

  // ---- B-frags: -2 * masked embeddings, position-stationary in registers ----
  bf16x8 bfrag[2][16];
  #pragma unroll
  for (int pt = 0; pt < 2; ++pt) {
    int pos = ptile * 256 + w * 64 + pt * 32 + l31;
    int id  = ids[pos];
    float m = (masks[pos] >= 1) ? -2.0f : 0.0f;
    const float* er = table + (size_t)id * D_ + 8 * h;
    #pragma unroll
    for (int s = 0; s < 16; ++s) {
      float4 x = *(const float4*)(er + 16 * s);
      float4 y = *(const float4*)(er + 16 * s + 4);
      bf16x8 b;
      b[0] = (__bf16)(x.x * m); b[1] = (__bf16)(x.y * m);
      b[2] = (__bf16)(x.z * m); b[3] = (__bf16)(x.w * m);
      b[4] = (__bf16)(y.x * m); b[5] = (__bf16)(y.y * m);
      b[6] = (__bf16)(y.z * m); b[7] = (__bf16)(y.w * m);
      bfrag[pt][s] = b;
    }
  }

  uint g0a = 0xFFFFFFFFu, g1a = 0xFFFFFFFFu;   // pos-tile 0: j<8 / j>=8 minima
  uint g0b = 0xFFFFFFFFu, g1b = 0xFFFFFFFFu;   // pos-tile 1

  const float* cnh = cnormR + (cu << 9);
  CN4 cnA = ldcn(cnh + h * 16);
  STAGE(0, cbuf0);
  __syncthreads();

  #pragma unroll 1
  for (int nc = 0; nc < NCH; nc += 2) {
    CN4 cnB = ldcn(cnh + (nc + 1) * 32 + h * 16);
    STAGE(nc + 1, cbuf1);
    PROCSEL(cbuf0, nc, cnA);
    __syncthreads();
    if (nc + 2 < NCH) {
      cnA = ldcn(cnh + (nc + 2) * 32 + h * 16);
      STAGE(nc + 2, cbuf0);
    }
    PROCSEL(cbuf1, nc + 1, cnB);
    __syncthreads();
  }

  // ---- endgame: h-partner merge, exact top-2 of 4 group minima ----
  #pragma unroll
  for (int pt = 0; pt < 2; ++pt) {
    uint x0 = pt ? g0b : g0a;
    uint x1 = pt ? g1b : g1a;
    uint o0 = __shfl_xor(x0, 32);
    uint o1 = __shfl_xor(x1, 32);
    uint a = min(x0, o0), A = max(x0, o0);
    uint b = min(x1, o1), B = max(x1, o1);
    uint m1 = min(a, b);
    uint m2 = min(max(a, b), min(A, B));
    int pos = ptile * 256 + w * 64 + pt * 32 + l31;
    if (h == 0) cand[(size_t)pos * 4 + cu] = make_uint2(m1, m2);
  }
}

// ---------------------------------------------------------------------------
// rescore_accum: grid = B*SEG blocks, 4 waves; wave-per-position: merge 8
// candidate keys (2 per cu), exact fp32 rescore of all 8, pick min with
// first-min tie-break; register accumulation, LDS cross-wave reduce, one
// global atomicAdd per dim per block.
// ---------------------------------------------------------------------------
#define SEG 10
#define PPB (L_ / SEG)          // 20 positions per block
#define PPW (PPB / 4)           // 5 per wave

__global__ __launch_bounds__(256) void rescore_accum_kernel(
    const int* __restrict__ ids, const int* __restrict__ masks,
    const float* __restrict__ table, const float* __restrict__ cb,
    const float* __restrict__ cnorm, const uint4* __restrict__ cand4,
    float* __restrict__ gacc, int* __restrict__ gcnt) {

    __shared__ float red_vq[4][D_];
    __shared__ float red_e[4][D_];
    __shared__ int   red_c[4];

    const int b   = blockIdx.x / SEG;
    const int seg = blockIdx.x % SEG;
    const int t = threadIdx.x;
    const int wv = t >> 6, lane = t & 63;

    float4 vqa = make_float4(0.f, 0.f, 0.f, 0.f);
    float4 ea  = make_float4(0.f, 0.f, 0.f, 0.f);
    int cnta = 0;

    #pragma unroll 1
    for (int i = 0; i < PPW; ++i) {
        int l = seg * PPB + wv * PPW + i;
        int u = b * L_ + l;
        uint4 ka = cand4[2 * u];
        uint4 kb = cand4[2 * u + 1];
        int k[8];
        k[0] = (int)(ka.x & 0x7FFu); k[1] = (int)(ka.y & 0x7FFu);
        k[2] = (int)(ka.z & 0x7FFu); k[3] = (int)(ka.w & 0x7FFu);
        k[4] = (int)(kb.x & 0x7FFu); k[5] = (int)(kb.y & 0x7FFu);
        k[6] = (int)(kb.z & 0x7FFu); k[7] = (int)(kb.w & 0x7FFu);

        int id = ids[u];
        bool mv = (masks[u] >= 1);
        float m = mv ? 1.0f : 0.0f;
        float4 e = ((const float4*)(table + (size_t)id * D_))[lane];
        e.x *= m; e.y *= m; e.z *= m; e.w *= m;

        float4 c[8];
        float  s[8];
        #pragma unroll
        for (int q = 0; q < 8; ++q) {
            c[q] = ((const float4*)(cb + (size_t)k[q] * D_))[lane];
            s[q] = fmaf(e.x, c[q].x, fmaf(e.y, c[q].y, fmaf(e.z, c[q].z, e.w * c[q].w)));
        }
        #pragma unroll
        for (int off = 32; off; off >>= 1) {
            #pragma unroll
            for (int q = 0; q < 8; ++q) s[q] += __shfl_xor(s[q], off);
        }

        float bs = cnorm[k[0]] - 2.0f * s[0];
        int   bk = k[0];
        float4 ch = c[0];
        #pragma unroll
        for (int q = 1; q < 8; ++q) {
            float sc = cnorm[k[q]] - 2.0f * s[q];
            bool better = (sc < bs) || (sc == bs && k[q] < bk);
            bs = better ? sc : bs;
            bk = better ? k[q] : bk;
            ch = better ? c[q] : ch;
        }
        vqa.x += ch.x; vqa.y += ch.y; vqa.z += ch.z; vqa.w += ch.w;
        ea.x += e.x; ea.y += e.y; ea.z += e.z; ea.w += e.w;
        cnta += mv ? 1 : 0;
    }

    *(float4*)&red_vq[wv][lane * 4] = vqa;
    *(float4*)&red_e[wv][lane * 4]  = ea;
    if (lane == 0) red_c[wv] = cnta;
    __syncthreads();

    float vs = red_vq[0][t] + red_vq[1][t] + red_vq[2][t] + red_vq[3][t];
    float es = red_e[0][t] + red_e[1][t] + red_e[2][t] + red_e[3][t];
    atomicAdd(&gacc[(size_t)b * (2 * D_) + t], vs);
    atomicAdd(&gacc[(size_t)b * (2 * D_) + D_ + t], es);
    if (t == 0) atomicAdd(&gcnt[b], red_c[0] + red_c[1] + red_c[2] + red_c[3]);
}

// ---------------------------------------------------------------------------
// dense: per-batch means + concat + GEMV.
// ---------------------------------------------------------------------------
__global__ __launch_bounds__(256) void dense_kernel(
    const float* __restrict__ gacc, const int* __restrict__ gcnt,
    const float* __restrict__ W, const float* __restrict__ bvec,
    float* __restrict__ out) {

    __shared__ float x[2 * D_];
    const int b = blockIdx.x;
    const int t = threadIdx.x;

    float fc = (float)gcnt[b];
    x[t]      = gacc[(size_t)b * (2 * D_) + t] / fc;                // vq_mean (no eps)
    x[D_ + t] = gacc[(size_t)b * (2 * D_) + D_ + t] / (fc + 1e-9f); // hist_mean
    __syncthreads();

    float acc = bvec[t];
    #pragma unroll 8
    for (int i = 0; i < 2 * D_; ++i)
        acc = fmaf(x[i], W[i * D_ + t], acc);
    out[(size_t)b * D_ + t] = acc;
}

// ---------------------------------------------------------------------------
extern "C" void kernel_launch(void* const* d_in, const int* in_sizes, int n_in,
                              void* d_out, int out_size, void* d_ws, size_t ws_size,
                              hipStream_t stream) {
    const int*   ids   = (const int*)  d_in[0];
    const int*   masks = (const int*)  d_in[1];
    const float* table = (const float*)d_in[2];
    const float* cb    = (const float*)d_in[3];
    const float* W     = (const float*)d_in[4];
    const float* bvec  = (const float*)d_in[5];
    float* out = (float*)d_out;

    char* p = (char*)d_ws;
    float*  cnorm  = (float*)p;             p += 8192;                  // 8 KB
    float*  cnormR = (float*)p;             p += 8192;                  // 8 KB
    ushort* cbbf   = (ushort*)p;            p += 1048576;               // 1 MB
    uint2*  cand   = (uint2*)p;             p += (size_t)BL_ * 4 * 8;   // 3.28 MB
    float*  gacc   = (float*)p;             p += (size_t)B_ * 2 * D_ * 4; // 1 MB
    int*    gcnt   = (int*)p;               p += B_ * 4;                // 2 KB

    hipMemsetAsync(gacc, 0, (size_t)B_ * 2 * D_ * 4 + B_ * 4, stream);

    prep_kernel<<<K_ * 64 / 256, 256, 0, stream>>>(cb, cnorm, cnormR, cbbf);
    gemm_top2_kernel<<<(BL_ / 256) * CUS, 256, 0, stream>>>(ids, masks, table, cbbf, cnormR, cand);
    rescore_accum_kernel<<<B_ * SEG, 256, 0, stream>>>(ids, masks, table, cb, cnorm,
                                                       (const uint4*)cand, gacc, gcnt);
    dense_kernel<<<B_, 256, 0, stream>>>(gacc, gcnt, W, bvec, out);
}

// Round 10
// 357.809 us; speedup vs baseline: 1.9725x; 1.9725x over previous
//
#include <hip/hip_runtime.h>
#include <hip/hip_bf16.h>
#include <cstddef>
#include <cstdint>

#define B_  512
#define L_  200
#define D_  256
#define K_  2048
#define BL_ (B_ * L_)

typedef __bf16 bf16x8 __attribute__((ext_vector_type(8)));
typedef float  f32x16 __attribute__((ext_vector_type(16)));

#define GL_LDS(g, l) __builtin_amdgcn_global_load_lds(                          \
    (const __attribute__((address_space(1))) void*)(g),                         \
    (__attribute__((address_space(3))) void*)(l), 16, 0, 0)

__device__ inline ushort f2bf(float f) {   // RNE float->bf16 (no NaN in data)
    union { float f; uint u; } a; a.f = f;
    uint r = a.u + 0x7FFFu + ((a.u >> 16) & 1u);
    return (ushort)(r >> 16);
}

// ---------------------------------------------------------------------------
// prep: cnorm[k] = ||c_k||^2 ; cnormR = acc-layout cnorm + 16 (positive-score
// bias; |2 e.c| <= 12 for this data); bf16 row-major codebook copy.
// acc row r = 4h + (j&3) + 8*(j>>2)  ->  cnormR[chunkbase + h*16 + j]
// ---------------------------------------------------------------------------
__global__ __launch_bounds__(256) void prep_kernel(const float* __restrict__ cb,
                                                   float* __restrict__ cnorm,
                                                   float* __restrict__ cnormR,
                                                   ushort* __restrict__ cbbf) {
    int code = (blockIdx.x * 256 + threadIdx.x) >> 6;
    int lane = threadIdx.x & 63;
    float4 v = ((const float4*)(cb + (size_t)code * D_))[lane];
    float s = v.x * v.x + v.y * v.y + v.z * v.z + v.w * v.w;
    #pragma unroll
    for (int off = 32; off; off >>= 1) s += __shfl_down(s, off);
    union { ushort us[4]; uint2 u2; } pk;
    pk.us[0] = f2bf(v.x); pk.us[1] = f2bf(v.y); pk.us[2] = f2bf(v.z); pk.us[3] = f2bf(v.w);
    ((uint2*)(cbbf + (size_t)code * D_))[lane] = pk.u2;
    if (lane == 0) {
        cnorm[code] = s;
        int r = code & 31;
        int h = (r >> 2) & 1;
        int j = (r & 3) | ((r >> 3) << 2);
        cnormR[(code & ~31) | (h << 4) | j] = s + 16.0f;
    }
}

// ---------------------------------------------------------------------------
// gemm_fused: R4 full-K structure (128 pos/block, 2 waves, 64 chunks LDS
// dbuf) + R7 packed-key top-2 + IN-BLOCK exact rescore + per-batch partial
// accumulation (global atomics). No cand buffer, no separate tail gather.
// ---------------------------------------------------------------------------
struct CN4 { float4 a, b, c, d; };

__device__ inline CN4 ldcn(const float* p) {
    CN4 r;
    r.a = ((const float4*)p)[0];
    r.b = ((const float4*)p)[1];
    r.c = ((const float4*)p)[2];
    r.d = ((const float4*)p)[3];
    return r;
}

#define STAGE(CIDX, BUF) {                                                      \
    int wub = __builtin_amdgcn_readfirstlane((t >> 6) * 512);                   \
    _Pragma("unroll")                                                           \
    for (int i_ = 0; i_ < 8; ++i_) {                                            \
      int slot = wub + i_ * 64 + (t & 63);                                      \
      int n_ = slot >> 5, up_ = slot & 31;                                      \
      int u_ = up_ ^ (n_ & 7);                                                  \
      GL_LDS(cbbf + (((size_t)(((CIDX) << 5) + n_)) << 8) + (u_ << 3),          \
             (char*)(BUF) + (size_t)(wub + i_ * 64) * 16);                      \
    } }

#define PROCSEL(BUF, NC, CN) {                                                  \
    f32x16 A0, A1;                                                              \
    A0[0]=(CN).a.x; A0[1]=(CN).a.y; A0[2]=(CN).a.z; A0[3]=(CN).a.w;             \
    A0[4]=(CN).b.x; A0[5]=(CN).b.y; A0[6]=(CN).b.z; A0[7]=(CN).b.w;             \
    A0[8]=(CN).c.x; A0[9]=(CN).c.y; A0[10]=(CN).c.z; A0[11]=(CN).c.w;           \
    A0[12]=(CN).d.x; A0[13]=(CN).d.y; A0[14]=(CN).d.z; A0[15]=(CN).d.w;         \
    A1 = A0;                                                                    \
    _Pragma("unroll")                                                           \
    for (int s_ = 0; s_ < 16; ++s_) {                                           \
      bf16x8 aF = *(const bf16x8*)((const char*)(BUF) +                         \
                    (((l31 << 5) + ((2 * s_ + h) ^ swz)) << 4));                \
      A0 = __builtin_amdgcn_mfma_f32_32x32x16_bf16(aF, bfrag[0][s_], A0, 0,0,0);\
      A1 = __builtin_amdgcn_mfma_f32_32x32x16_bf16(aF, bfrag[1][s_], A1, 0,0,0);\
    }                                                                           \
    uint kbase = ((uint)(NC) << 5) | h4;                                        \
    _Pragma("unroll")                                                           \
    for (int jp_ = 0; jp_ < 8; ++jp_) {                                         \
      int j0_ = 2 * jp_, j1_ = 2 * jp_ + 1;                                     \
      uint c0_ = kbase + (uint)((j0_ & 3) + 8 * (j0_ >> 2));                    \
      uint c1_ = kbase + (uint)((j1_ & 3) + 8 * (j1_ >> 2));                    \
      {                                                                         \
        uint ka = (__float_as_uint(A0[j0_]) & 0xFFFFF800u) | c0_;               \
        uint kb = (__float_as_uint(A0[j1_]) & 0xFFFFF800u) | c1_;               \
        uint lo = min(ka, kb), hi = max(ka, kb);                                \
        uint tt = max(b1a, lo);                                                 \
        b1a = min(b1a, lo);                                                     \
        b2a = min(min(b2a, tt), hi);                                            \
      }                                                                         \
      {                                                                         \
        uint ka = (__float_as_uint(A1[j0_]) & 0xFFFFF800u) | c0_;               \
        uint kb = (__float_as_uint(A1[j1_]) & 0xFFFFF800u) | c1_;               \
        uint lo = min(ka, kb), hi = max(ka, kb);                                \
        uint tt = max(b1b, lo);                                                 \
        b1b = min(b1b, lo);                                                     \
        b2b = min(min(b2b, tt), hi);                                            \
      }                                                                         \
    } }

__global__ __launch_bounds__(128, 2) void gemm_fused_kernel(
    const int* __restrict__ ids, const int* __restrict__ masks,
    const float* __restrict__ table, const ushort* __restrict__ cbbf,
    const float* __restrict__ cnormR, const float* __restrict__ cnorm,
    const float* __restrict__ cb,
    float* __restrict__ gacc, int* __restrict__ gcnt) {

  __shared__ ushort cbuf0[32 * 256];   // 16 KB
  __shared__ ushort cbuf1[32 * 256];   // 16 KB
  __shared__ uint  key1s[128], key2s[128];
  __shared__ int   ids_s[128];
  __shared__ float mask_s[128];
  __shared__ int   qidx_s[128];
  __shared__ int   cnt01[2];

  const int t    = threadIdx.x;
  const int lane = t & 63;
  const int l31  = lane & 31;
  const int h    = lane >> 5;
  const int w    = t >> 6;
  const int P0   = blockIdx.x * 128;
  const int swz  = l31 & 7;
  const uint h4  = (uint)(h << 2);

  if (t < 2) cnt01[t] = 0;

  // ---- B-frags: -2 * masked embeddings, position-stationary in registers ----
  bf16x8 bfrag[2][16];
  #pragma unroll
  for (int pt = 0; pt < 2; ++pt) {
    int pl  = w * 64 + pt * 32 + l31;
    int pos = P0 + pl;
    int id  = ids[pos];
    bool mv = (masks[pos] >= 1);
    if (h == 0) { ids_s[pl] = id; mask_s[pl] = mv ? 1.0f : 0.0f; }
    float m = mv ? -2.0f : 0.0f;
    const float* er = table + (size_t)id * D_ + 8 * h;
    #pragma unroll
    for (int s = 0; s < 16; ++s) {
      float4 x = *(const float4*)(er + 16 * s);
      float4 y = *(const float4*)(er + 16 * s + 4);
      bf16x8 b;
      b[0] = (__bf16)(x.x * m); b[1] = (__bf16)(x.y * m);
      b[2] = (__bf16)(x.z * m); b[3] = (__bf16)(x.w * m);
      b[4] = (__bf16)(y.x * m); b[5] = (__bf16)(y.y * m);
      b[6] = (__bf16)(y.z * m); b[7] = (__bf16)(y.w * m);
      bfrag[pt][s] = b;
    }
  }

  uint b1a = 0xFFFFFFFFu, b2a = 0xFFFFFFFFu;
  uint b1b = 0xFFFFFFFFu, b2b = 0xFFFFFFFFu;

  STAGE(0, cbuf0);
  __syncthreads();
  CN4 cnA = ldcn(cnormR + h * 16);

  #pragma unroll 1
  for (int nc = 0; nc < 64; nc += 2) {
    CN4 cnB = ldcn(cnormR + (nc + 1) * 32 + h * 16);
    STAGE(nc + 1, cbuf1);
    PROCSEL(cbuf0, nc, cnA);
    __syncthreads();
    if (nc + 2 < 64) {
      cnA = ldcn(cnormR + (nc + 2) * 32 + h * 16);
      STAGE(nc + 2, cbuf0);
    }
    PROCSEL(cbuf1, nc + 1, cnB);
    __syncthreads();
  }

  // ---- h-partner merge -> top-2 keys per position -> LDS ----
  #pragma unroll
  for (int pt = 0; pt < 2; ++pt) {
    uint x1 = pt ? b1b : b1a;
    uint x2 = pt ? b2b : b2a;
    uint o1 = __shfl_xor(x1, 32);
    uint o2 = __shfl_xor(x2, 32);
    uint m1 = min(x1, o1);
    uint m2 = min(min(max(x1, o1), x2), o2);
    int pl = w * 64 + pt * 32 + l31;
    if (h == 0) { key1s[pl] = m1; key2s[pl] = m2; }
  }
  __syncthreads();

  // ---- in-block exact rescore: 4 passes x 16 positions x 4 lanes ----
  #pragma unroll 1
  for (int g = 0; g < 4; ++g) {
    int pl  = w * 64 + g * 16 + (lane >> 2);
    int sub = lane & 3;
    int k1 = (int)(key1s[pl] & 0x7FFu);
    int k2 = (int)(key2s[pl] & 0x7FFu);
    int id = ids_s[pl];
    float m = mask_s[pl];
    const float4* ep  = (const float4*)(table + (size_t)id * D_ + sub * 64);
    const float4* c1p = (const float4*)(cb + (size_t)k1 * D_ + sub * 64);
    const float4* c2p = (const float4*)(cb + (size_t)k2 * D_ + sub * 64);
    float d1 = 0.f, d2 = 0.f;
    #pragma unroll
    for (int i = 0; i < 16; ++i) {
      float4 e = ep[i];
      float4 a = c1p[i];
      float4 b = c2p[i];
      d1 = fmaf(e.x, a.x, fmaf(e.y, a.y, fmaf(e.z, a.z, fmaf(e.w, a.w, d1))));
      d2 = fmaf(e.x, b.x, fmaf(e.y, b.y, fmaf(e.z, b.z, fmaf(e.w, b.w, d2))));
    }
    d1 += __shfl_xor(d1, 1); d1 += __shfl_xor(d1, 2);
    d2 += __shfl_xor(d2, 1); d2 += __shfl_xor(d2, 2);
    if (sub == 0) {
      float s1 = cnorm[k1] - 2.0f * m * d1;
      float s2 = cnorm[k2] - 2.0f * m * d2;
      qidx_s[pl] = (s2 < s1 || (s2 == s1 && k2 < k1)) ? k2 : k1;  // first-min
    }
  }
  __syncthreads();

  // ---- gather-sum: thread t owns dims 2t,2t+1; batch-boundary split ----
  const int bA = P0 / L_;
  const int bB = bA + 1;
  int split = (bA + 1) * L_ - P0;
  if (split > 128) split = 128;

  float2 vq0 = {0.f, 0.f}, e0 = {0.f, 0.f};
  float2 vq1 = {0.f, 0.f}, e1 = {0.f, 0.f};

  #pragma unroll 4
  for (int l = 0; l < split; ++l) {
    int q = qidx_s[l]; int idl = ids_s[l]; float ml = mask_s[l];
    float2 cv = *(const float2*)(cb + (size_t)q * D_ + 2 * t);
    float2 ev = *(const float2*)(table + (size_t)idl * D_ + 2 * t);
    vq0.x += cv.x; vq0.y += cv.y;
    e0.x = fmaf(ml, ev.x, e0.x); e0.y = fmaf(ml, ev.y, e0.y);
  }
  #pragma unroll 4
  for (int l = split; l < 128; ++l) {
    int q = qidx_s[l]; int idl = ids_s[l]; float ml = mask_s[l];
    float2 cv = *(const float2*)(cb + (size_t)q * D_ + 2 * t);
    float2 ev = *(const float2*)(table + (size_t)idl * D_ + 2 * t);
    vq1.x += cv.x; vq1.y += cv.y;
    e1.x = fmaf(ml, ev.x, e1.x); e1.y = fmaf(ml, ev.y, e1.y);
  }

  // counts
  {
    int p1 = (t >= split) ? 1 : 0;
    if (mask_s[t] != 0.f) atomicAdd(&cnt01[p1], 1);
  }
  __syncthreads();

  // ---- global accumulation ----
  {
    float* g0 = gacc + (size_t)bA * (2 * D_);
    atomicAdd(g0 + 2 * t,            vq0.x);
    atomicAdd(g0 + 2 * t + 1,        vq0.y);
    atomicAdd(g0 + D_ + 2 * t,       e0.x);
    atomicAdd(g0 + D_ + 2 * t + 1,   e0.y);
    if (split < 128) {
      float* g1 = gacc + (size_t)bB * (2 * D_);
      atomicAdd(g1 + 2 * t,          vq1.x);
      atomicAdd(g1 + 2 * t + 1,      vq1.y);
      atomicAdd(g1 + D_ + 2 * t,     e1.x);
      atomicAdd(g1 + D_ + 2 * t + 1, e1.y);
    }
    if (t == 0) {
      atomicAdd(&gcnt[bA], cnt01[0]);
      if (split < 128) atomicAdd(&gcnt[bB], cnt01[1]);
    }
  }
}

// ---------------------------------------------------------------------------
// dense: per-batch means + concat + GEMV.
// ---------------------------------------------------------------------------
__global__ __launch_bounds__(256) void dense_kernel(
    const float* __restrict__ gacc, const int* __restrict__ gcnt,
    const float* __restrict__ W, const float* __restrict__ bvec,
    float* __restrict__ out) {

    __shared__ float x[2 * D_];
    const int b = blockIdx.x;
    const int t = threadIdx.x;

    float fc = (float)gcnt[b];
    x[t]      = gacc[(size_t)b * (2 * D_) + t] / fc;                // vq_mean (no eps)
    x[D_ + t] = gacc[(size_t)b * (2 * D_) + D_ + t] / (fc + 1e-9f); // hist_mean
    __syncthreads();

    float acc = bvec[t];
    #pragma unroll 8
    for (int i = 0; i < 2 * D_; ++i)
        acc = fmaf(x[i], W[i * D_ + t], acc);
    out[(size_t)b * D_ + t] = acc;
}

// ---------------------------------------------------------------------------
extern "C" void kernel_launch(void* const* d_in, const int* in_sizes, int n_in,
                              void* d_out, int out_size, void* d_ws, size_t ws_size,
                              hipStream_t stream) {
    const int*   ids   = (const int*)  d_in[0];
    const int*   masks = (const int*)  d_in[1];
    const float* table = (const float*)d_in[2];
    const float* cb    = (const float*)d_in[3];
    const float* W     = (const float*)d_in[4];
    const float* bvec  = (const float*)d_in[5];
    float* out = (float*)d_out;

    char* p = (char*)d_ws;
    float*  cnorm  = (float*)p;             p += 8192;                  // 8 KB
    float*  cnormR = (float*)p;             p += 8192;                  // 8 KB
    ushort* cbbf   = (ushort*)p;            p += 1048576;               // 1 MB
    float*  gacc   = (float*)p;             p += (size_t)B_ * 2 * D_ * 4; // 1 MB
    int*    gcnt   = (int*)p;               p += B_ * 4;                // 2 KB

    hipMemsetAsync(gacc, 0, (size_t)B_ * 2 * D_ * 4 + B_ * 4, stream);

    prep_kernel<<<K_ * 64 / 256, 256, 0, stream>>>(cb, cnorm, cnormR, cbbf);
    gemm_fused_kernel<<<BL_ / 128, 128, 0, stream>>>(ids, masks, table, cbbf, cnormR,
                                                     cnorm, cb, gacc, gcnt);
    dense_kernel<<<B_, 256, 0, stream>>>(gacc, gcnt, W, bvec, out);
}